// Round 1
// 437.191 us; speedup vs baseline: 1.0115x; 1.0115x over previous
//
#include <hip/hip_runtime.h>

#define L 1024
#define BLOCK 256   // 4 waves, 1 row per wave

__device__ __forceinline__ float soft_thr(float c, float thr) {
    float a = fabsf(c);
    return (a >= thr) ? copysignf(a - thr, c) : 0.0f;
}

__device__ __forceinline__ int imin2(int a, int b) { return (a < b) ? a : b; }
__device__ __forceinline__ int imax2(int a, int b) { return (a > b) ? a : b; }

__global__ __launch_bounds__(BLOCK) void wavelet_denoise_kernel(
        const float* __restrict__ x, float* __restrict__ out) {
    constexpr float IS2 = 0.70710678118654752f;
    constexpr float SQRT_2LOGL = 3.7232974111f;   // f32(sqrt(2*ln(1024)))

    const int lane = threadIdx.x & 63;
    const int wid  = threadIdx.x >> 6;
    const long long row = (long long)blockIdx.x * 4 + wid;
    const float* xr = x + row * L;
    float* orow = out + row * L;

    // ---- load: 4 coalesced float4 chunks; chunk j = elements (j*64+lane)*4 .. +3
    float4 in[4];
    #pragma unroll
    for (int j = 0; j < 4; ++j)
        in[j] = ((const float4*)xr)[j * 64 + lane];

    // ---- level 1 DWT: lane owns ca1/cd1 pair indices {128j + 2*lane, +1}
    float ca1[8], cd1[8];
    #pragma unroll
    for (int j = 0; j < 4; ++j) {
        ca1[2*j]   = (in[j].x + in[j].y) * IS2;
        cd1[2*j]   = (in[j].x - in[j].y) * IS2;
        ca1[2*j+1] = (in[j].z + in[j].w) * IS2;
        cd1[2*j+1] = (in[j].z - in[j].w) * IS2;
    }

    // ---- level 2: lane owns ca2/cd2 at index 64j + lane (local pairs)
    float ca2[4], cd2[4];
    #pragma unroll
    for (int j = 0; j < 4; ++j) {
        ca2[j] = (ca1[2*j] + ca1[2*j+1]) * IS2;
        cd2[j] = (ca1[2*j] - ca1[2*j+1]) * IS2;
    }

    // ---- level 3: adjacent-lane combine; even lane 2m holds ca3/cd3[32j + m]
    float ca3[4], cd3[4];
    #pragma unroll
    for (int j = 0; j < 4; ++j) {
        float o = __shfl_xor(ca2[j], 1);
        ca3[j] = (ca2[j] + o) * IS2;   // valid on even lanes (odd lanes: unused garbage)
        cd3[j] = (ca2[j] - o) * IS2;
    }

    // ---- exact median of 512 |cd1| -------------------------------------------
    // Direction-encoded integer bitonic: keys are bit patterns of |cd1| (non-neg
    // floats -> monotone as signed int). Sorting "direction" for element
    // i = lane*8 + r at phase k depends only on bit log2(k) of i; for k >= 8
    // that's a lane bit, so we fold it into the key with w = u ^ M (M = 0 or ~0
    // per lane). Every compare-exchange then becomes lower-keeps-min:
    //   - in-lane CEs: pure min/max, no cndmask, no direction logic
    //   - cross-lane CEs: one uniform (lane & lmask) select per stage
    // Final phase k=512 truncated: after the j=256 bitonic split, the lower 256
    // elements are exactly the smallest 256, so
    //   sorted[255] = max(lower half), sorted[256] = min(upper half).
    int w[8];
    const int b0 = -(int)( lane       & 1);   // M_8
    const int b1 = -(int)((lane >> 1) & 1);   // M_16
    const int b2 = -(int)((lane >> 2) & 1);   // M_32
    const int b3 = -(int)((lane >> 3) & 1);   // M_64
    const int b4 = -(int)((lane >> 4) & 1);   // M_128
    const int b5 = -(int)((lane >> 5) & 1);   // M_256

    #pragma unroll
    for (int r = 0; r < 8; ++r)
        w[r] = (__float_as_int(cd1[r]) & 0x7fffffff) ^ b0;

    #define CE(a, c) { int _lo = imin2(w[a], w[c]); int _hi = imax2(w[a], w[c]); \
                       w[a] = _lo; w[c] = _hi; }

    // in-lane Batcher odd-even mergesort of 8 (19 CEs), ascending in w-space
    CE(0,1) CE(2,3) CE(4,5) CE(6,7)
    CE(0,2) CE(1,3) CE(4,6) CE(5,7)
    CE(1,2) CE(5,6)
    CE(0,4) CE(1,5) CE(2,6) CE(3,7)
    CE(2,4) CE(3,5)
    CE(1,2) CE(3,4) CE(5,6)

    #define XORW(T) { const int _t = (T); \
        _Pragma("unroll") for (int r = 0; r < 8; ++r) w[r] ^= _t; }

    #define CROSS_STAGE(LM) { const bool _up = (lane & (LM)) != 0; \
        _Pragma("unroll") for (int r = 0; r < 8; ++r) { \
            int _o = __shfl_xor(w[r], (LM)); \
            w[r] = _up ? imax2(w[r], _o) : imin2(w[r], _o); } }

    // in-lane merge stages j = 4, 2, 1 (lower index keeps min in w-space)
    #define INLANE3() { \
        CE(0,4) CE(1,5) CE(2,6) CE(3,7) \
        CE(0,2) CE(1,3) CE(4,6) CE(5,7) \
        CE(0,1) CE(2,3) CE(4,5) CE(6,7) }

    XORW(b0 ^ b1); CROSS_STAGE(1);                                                             INLANE3();  // k=16
    XORW(b1 ^ b2); CROSS_STAGE(2);  CROSS_STAGE(1);                                            INLANE3();  // k=32
    XORW(b2 ^ b3); CROSS_STAGE(4);  CROSS_STAGE(2); CROSS_STAGE(1);                            INLANE3();  // k=64
    XORW(b3 ^ b4); CROSS_STAGE(8);  CROSS_STAGE(4); CROSS_STAGE(2); CROSS_STAGE(1);            INLANE3();  // k=128
    XORW(b4 ^ b5); CROSS_STAGE(16); CROSS_STAGE(8); CROSS_STAGE(4); CROSS_STAGE(2); CROSS_STAGE(1); INLANE3();  // k=256
    XORW(b5);      CROSS_STAGE(32);   // k=512 bitonic split only (now in u-space)

    // ranks 255/256: max of lower 256 / min of upper 256
    int zmx = imax2(imax2(imax2(w[0], w[1]), imax2(w[2], w[3])),
                    imax2(imax2(w[4], w[5]), imax2(w[6], w[7])));
    int zmn = imin2(imin2(imin2(w[0], w[1]), imin2(w[2], w[3])),
                    imin2(imin2(w[4], w[5]), imin2(w[6], w[7])));
    int z = (lane & 32) ? ~zmn : zmx;   // upper half reduces min via bitwise-NOT trick
    #pragma unroll
    for (int m = 1; m <= 16; m <<= 1)
        z = imax2(z, __shfl_xor(z, m));
    const float m0 = __int_as_float(__shfl(z, 0));      // sorted[255]
    const float m1 = __int_as_float(~__shfl(z, 32));    // sorted[256]

    #undef CE
    #undef XORW
    #undef CROSS_STAGE
    #undef INLANE3

    const float median = 0.5f * (m0 + m1);
    const float lam  = (median / 0.6745f) * SQRT_2LOGL;
    const float thr1 = lam;                      // / log2(2)
    const float thr2 = lam / 1.5849625007f;      // / log2(3)
    const float thr3 = lam * 0.5f;               // / log2(4)

    // ---- reconstruction (all local / single shuffle per level-3 fetch)
    #pragma unroll
    for (int j = 0; j < 4; ++j) {
        // ca2r[64j+lane] needs ca3/cd3[32j + lane/2], held in lane (lane & ~1)
        float c3 = __shfl(ca3[j], lane & 62);
        float d3 = soft_thr(__shfl(cd3[j], lane & 62), thr3);
        float ca2r = ((lane & 1) == 0) ? (c3 + d3) * IS2 : (c3 - d3) * IS2;

        float d2 = soft_thr(cd2[j], thr2);
        float ca1r0 = (ca2r + d2) * IS2;
        float ca1r1 = (ca2r - d2) * IS2;

        float d10 = soft_thr(cd1[2*j],   thr1);
        float d11 = soft_thr(cd1[2*j+1], thr1);
        float4 o;
        o.x = (ca1r0 + d10) * IS2;
        o.y = (ca1r0 - d10) * IS2;
        o.z = (ca1r1 + d11) * IS2;
        o.w = (ca1r1 - d11) * IS2;
        ((float4*)orow)[j * 64 + lane] = o;
    }
}

extern "C" void kernel_launch(void* const* d_in, const int* in_sizes, int n_in,
                              void* d_out, int out_size, void* d_ws, size_t ws_size,
                              hipStream_t stream) {
    const float* x = (const float*)d_in[0];
    float* out = (float*)d_out;
    const int rows = in_sizes[0] / L;           // 65536
    wavelet_denoise_kernel<<<rows / 4, BLOCK, 0, stream>>>(x, out);
}